// Round 10
// baseline (455.553 us; speedup 1.0000x reference)
//
#include <hip/hip_runtime.h>

// Problem constants (fixed by the reference setup).
#define BATCH  256
#define SEQT   2048
#define LAYERS 4
#define HID    64
#define CHUNK  16                        // timesteps per barrier phase
#define PHASES (SEQT / CHUNK + LAYERS - 1)
#define BPB    2                         // batches per block -> 2 chains/SIMD
#define GRID   (BATCH / BPB)             // 128 blocks
#define NTHR   (BPB * LAYERS * 64)       // 512 threads / 8 waves
// P (input / projected hidden size) == 1

#define LOG2E  1.4426950408889634f
#define K2     (2.0f * LOG2E)            // c is carried as C = K2 * c

__device__ __forceinline__ float fast_rcp(float x) {
    return __builtin_amdgcn_rcpf(x);
}
__device__ __forceinline__ float fast_exp2(float x) {
    return __builtin_amdgcn_exp2f(x);    // raw v_exp_f32 (2^x)
}

// One DPP-shifted add: v += dpp_move(v). bound_ctrl=true -> invalid lanes read 0.
#define DPP_ADD(v, ctrl)                                                     \
    (v) += __int_as_float(__builtin_amdgcn_update_dpp(                       \
        0, __float_as_int(v), (ctrl), 0xF, 0xF, true))

// Full wave64 sum via DPP row reduce + row broadcasts; total lands in lane 63.
__device__ __forceinline__ float wave_sum_lane63(float v) {
    DPP_ADD(v, 0x111);   // row_shr:1
    DPP_ADD(v, 0x112);   // row_shr:2
    DPP_ADD(v, 0x114);   // row_shr:4
    DPP_ADD(v, 0x118);   // row_shr:8 -> lanes 15/31/47/63 = row sums
    DPP_ADD(v, 0x142);   // row_bcast:15
    DPP_ADD(v, 0x143);   // row_bcast:31 -> lane 63 = full sum
    return v;
}

// 2 batches x 4 layers = 8 waves per block; wave w: batch-in-block = w>>2,
// layer = w&3, lane k = hidden unit. Each SIMD hosts 2 waves with INDEPENDENT
// recurrence chains (batches), so one chain's trans-latency stalls are filled
// by the other chain's issue. (R6 showed 4 chains/SIMD over-subscribes issue;
// R9 showed 1 chain/SIMD leaves ~40% stall -- this probes the midpoint.)
// Software pipeline across time in CHUNK-step phases; inter-layer h via
// double-buffered LDS; outputs LDS-buffered, flushed once; phase body is one
// basic block with a cndmask collector. 7 transcendentals/step.
__global__ __launch_bounds__(NTHR, 1) void lstm_pipeline_kernel(
    const float* __restrict__ y,      // [B, T, 1]
    const float* __restrict__ W_ih,   // [L, 4H, 1]
    const float* __restrict__ W_hh,   // [L, 4H, 1]
    const float* __restrict__ b_ih,   // [L, 4H]
    const float* __restrict__ b_hh,   // [L, 4H]
    const float* __restrict__ W_hr,   // [L, 1, H]
    const int*  __restrict__ msl_p,   // min_seq_len scalar
    float* __restrict__ out)          // [B, T - msl, 1]
{
    const int tid = threadIdx.x;
    const int w   = tid >> 6;
    const int bi  = w >> 2;     // batch within block (0..1)
    const int l   = w & 3;      // layer
    const int k   = tid & 63;   // hidden unit / lane
    const int b   = blockIdx.x * BPB + bi;
    const int msl = *msl_p;

    __shared__ float y_lds[BPB][SEQT];                           // 16 KB
    __shared__ float out_lds[BPB][SEQT];                         // 16 KB
    __shared__ __align__(16) float h_buf[2][BPB][LAYERS][CHUNK]; // 1 KB

    // Stage y rows into LDS with float4 loads (each half-block does one row).
    {
        const int sb = tid >> 8;            // 0..1: which batch row
        const int st = tid & 255;
        const float4* y4  = (const float4*)(y + (size_t)(blockIdx.x * BPB + sb) * SEQT);
        float4*       yl4 = (float4*)&y_lds[sb][0];
        #pragma unroll
        for (int i = st; i < SEQT / 4; i += 256) yl4[i] = y4[i];
    }

    // Loop-invariant weights. Gate order: i, f, g, o.
    // i, f, o carry -log2e (exp2 -> e^-gate); g carries 2*log2e (exp2 -> e^{2g}).
    const int wbase = l * 4 * HID;
    const float wi0 = -LOG2E * W_ih[wbase + 0 * HID + k];
    const float wi1 = -LOG2E * W_ih[wbase + 1 * HID + k];
    const float wi2 =  K2    * W_ih[wbase + 2 * HID + k];
    const float wi3 = -LOG2E * W_ih[wbase + 3 * HID + k];
    const float wh0 = -LOG2E * W_hh[wbase + 0 * HID + k];
    const float wh1 = -LOG2E * W_hh[wbase + 1 * HID + k];
    const float wh2 =  K2    * W_hh[wbase + 2 * HID + k];
    const float wh3 = -LOG2E * W_hh[wbase + 3 * HID + k];
    const float bb0 = -LOG2E * (b_ih[wbase + 0 * HID + k] + b_hh[wbase + 0 * HID + k]);
    const float bb1 = -LOG2E * (b_ih[wbase + 1 * HID + k] + b_hh[wbase + 1 * HID + k]);
    const float bb2 =  K2    * (b_ih[wbase + 2 * HID + k] + b_hh[wbase + 2 * HID + k]);
    const float bb3 = -LOG2E * (b_ih[wbase + 3 * HID + k] + b_hh[wbase + 3 * HID + k]);
    const float wr  = W_hr[l * HID + k];

    float h = 0.0f;   // projected hidden (wave-uniform)
    float C = 0.0f;   // cell state, scaled: C = 2*log2e*c

    for (int p = 0; p < PHASES; ++p) {
        __syncthreads();   // publishes previous phase's h_buf writes (LDS only)
        const int t0 = (p - l) * CHUNK;
        if (t0 >= 0 && t0 < SEQT) {
            // Fetch this chunk's 16 scalar inputs (wave-uniform broadcast reads).
            float4 xv[CHUNK / 4];
            if (l == 0) {
                const float4* ys = (const float4*)&y_lds[bi][t0];
                #pragma unroll
                for (int q = 0; q < CHUNK / 4; ++q) xv[q] = ys[q];
            } else {
                const float4* hb = (const float4*)&h_buf[(p - 1) & 1][bi][l - 1][0];
                #pragma unroll
                for (int q = 0; q < CHUNK / 4; ++q) xv[q] = hb[q];
            }
            float xs[CHUNK];
            #pragma unroll
            for (int q = 0; q < CHUNK / 4; ++q) {
                xs[4 * q + 0] = xv[q].x; xs[4 * q + 1] = xv[q].y;
                xs[4 * q + 2] = xv[q].z; xs[4 * q + 3] = xv[q].w;
            }

            // Input-side gate contributions: independent of h, off the chain.
            float p0[CHUNK], p1[CHUNK], p2[CHUNK], p3[CHUNK];
            #pragma unroll
            for (int j = 0; j < CHUNK; ++j) {
                p0[j] = fmaf(xs[j], wi0, bb0);
                p1[j] = fmaf(xs[j], wi1, bb1);
                p2[j] = fmaf(xs[j], wi2, bb2);
                p3[j] = fmaf(xs[j], wi3, bb3);
            }

            // Collector: lane j ends up holding step j's h (branch-free select).
            float hcol = 0.0f;

            #pragma unroll
            for (int j = 0; j < CHUNK; ++j) {
                // Gate pre-activations (scale factors pre-folded into weights).
                const float gi = fmaf(h, wh0, p0[j]);
                const float gf = fmaf(h, wh1, p1[j]);
                const float gg = fmaf(h, wh2, p2[j]);
                const float go = fmaf(h, wh3, p3[j]);

                const float Ei = fast_exp2(gi);     // e^-i
                const float Ef = fast_exp2(gf);     // e^-f
                const float Eg = fast_exp2(gg);     // e^{2g}
                const float Eo = fast_exp2(go);     // e^-o

                // Merged c-update: one reciprocal for sf*C + si*tanh(g)*K2.
                const float ai     = 1.0f + Ei;
                const float ag     = 1.0f + Eg;
                const float af     = 1.0f + Ef;
                const float den_ig = ai * ag;
                const float tg     = fmaf(K2, Eg, -K2);   // K2(Eg-1)
                const float tgf    = tg * af;             // K2(Eg-1)(1+Ef)
                const float num    = fmaf(C, den_ig, tgf);
                const float den    = den_ig * af;
                C = num * fast_rcp(den);

                // Output: v = wr(Ec-1)/((1+Eo)(1+Ec)), one reciprocal.
                const float Ec   = fast_exp2(C);          // e^{2c}
                const float ao   = 1.0f + Eo;
                const float ac   = 1.0f + Ec;
                const float den2 = ao * ac;
                const float num2 = fmaf(wr, Ec, -wr);     // wr(Ec-1)
                const float v    = num2 * fast_rcp(den2);

                const float vs = wave_sum_lane63(v);      // lane 63 = sum

                // Wave-uniform h for the next step (readlane -> SGPR).
                h = __int_as_float(
                    __builtin_amdgcn_readlane(__float_as_int(vs), 63));

                // Deposit into lane j of the collector -- no branch.
                hcol = (k == j) ? h : hcol;
            }

            // One masked LDS store per phase (lanes 0..15 hold steps 0..15).
            if (k < CHUNK) {
                if (l < LAYERS - 1) h_buf[p & 1][bi][l][k] = hcol;
                else                out_lds[bi][t0 + k]    = hcol;
            }
        }
    }

    // Flush buffered outputs to global once (coalesced per 256-thread group).
    __syncthreads();
    const int nout = SEQT - msl;
    const int fb   = tid >> 8;            // batch within block (0..1)
    const int ft   = tid & 255;
    float* outb = out + (size_t)(blockIdx.x * BPB + fb) * nout;
    for (int i = ft; i < nout; i += 256) outb[i] = out_lds[fb][i + msl];
}

extern "C" void kernel_launch(void* const* d_in, const int* in_sizes, int n_in,
                              void* d_out, int out_size, void* d_ws, size_t ws_size,
                              hipStream_t stream) {
    const float* y    = (const float*)d_in[0];
    const float* W_ih = (const float*)d_in[1];
    const float* W_hh = (const float*)d_in[2];
    const float* b_ih = (const float*)d_in[3];
    const float* b_hh = (const float*)d_in[4];
    const float* W_hr = (const float*)d_in[5];
    const int*   msl  = (const int*)d_in[6];
    float* out = (float*)d_out;

    lstm_pipeline_kernel<<<GRID, NTHR, 0, stream>>>(
        y, W_ih, W_hh, b_ih, b_hh, W_hr, msl, out);
}

// Round 11
// 404.129 us; speedup vs baseline: 1.1272x; 1.1272x over previous
//
#include <hip/hip_runtime.h>

// Problem constants (fixed by the reference setup).
#define BATCH  256
#define SEQT   2048
#define LAYERS 4
#define HID    64
#define CHUNK  16                        // timesteps per barrier phase
#define PHASES (SEQT / CHUNK + LAYERS - 1)
#define BPW    2                         // batches per WAVE (in-wave interleave)
#define GRID   (BATCH / BPW)             // 128 blocks
// P (input / projected hidden size) == 1

#define LOG2E  1.4426950408889634f
#define K2     (2.0f * LOG2E)            // c is carried as C = K2 * c

__device__ __forceinline__ float fast_rcp(float x) {
    return __builtin_amdgcn_rcpf(x);
}
__device__ __forceinline__ float fast_exp2(float x) {
    return __builtin_amdgcn_exp2f(x);    // raw v_exp_f32 (2^x)
}

// One DPP-shifted add: v += dpp_move(v). bound_ctrl=true -> invalid lanes read 0.
#define DPP_ADD(v, ctrl)                                                     \
    (v) += __int_as_float(__builtin_amdgcn_update_dpp(                       \
        0, __float_as_int(v), (ctrl), 0xF, 0xF, true))

// Full wave64 sum via DPP row reduce + row broadcasts; total lands in lane 63.
__device__ __forceinline__ float wave_sum_lane63(float v) {
    DPP_ADD(v, 0x111);   // row_shr:1
    DPP_ADD(v, 0x112);   // row_shr:2
    DPP_ADD(v, 0x114);   // row_shr:4
    DPP_ADD(v, 0x118);   // row_shr:8 -> lanes 15/31/47/63 = row sums
    DPP_ADD(v, 0x142);   // row_bcast:15
    DPP_ADD(v, 0x143);   // row_bcast:31 -> lane 63 = full sum
    return v;
}

// One block = 2 batches, 4 waves = 4 layers, 1 wave/SIMD (measured optimum:
// R6/R10 showed SIMD-sharing via extra waves multiplies issue cost faster
// than it hides stalls). Each WAVE carries TWO independent recurrence chains
// (batches A and B) for its layer: the SIMD issues in order within a wave, so
// chain-A trans/DPP latency windows are filled by chain-B instructions that
// the compiler can statically interleave -- no wave arbitration involved.
// Weights are shared between the chains (same layer). Software pipeline
// across time in CHUNK-step phases; inter-layer h via double-buffered LDS;
// outputs LDS-buffered, flushed once; phase body is one basic block with
// cndmask collectors. 7 transcendentals per step per chain.
__global__ __launch_bounds__(256, 1) void lstm_pipeline_kernel(
    const float* __restrict__ y,      // [B, T, 1]
    const float* __restrict__ W_ih,   // [L, 4H, 1]
    const float* __restrict__ W_hh,   // [L, 4H, 1]
    const float* __restrict__ b_ih,   // [L, 4H]
    const float* __restrict__ b_hh,   // [L, 4H]
    const float* __restrict__ W_hr,   // [L, 1, H]
    const int*  __restrict__ msl_p,   // min_seq_len scalar
    float* __restrict__ out)          // [B, T - msl, 1]
{
    const int tid = threadIdx.x;
    const int l   = tid >> 6;   // layer / wave id
    const int k   = tid & 63;   // hidden unit / lane
    const int msl = *msl_p;

    __shared__ float y_lds[BPW][SEQT];                           // 16 KB
    __shared__ float out_lds[BPW][SEQT];                         // 16 KB
    __shared__ __align__(16) float h_buf[2][BPW][LAYERS][CHUNK]; //  1 KB

    // Stage both y rows into LDS with float4 loads.
    {
        const int sb = tid >> 7;            // 0..1: which batch row
        const int st = tid & 127;
        const float4* y4  = (const float4*)(y + (size_t)(blockIdx.x * BPW + sb) * SEQT);
        float4*       yl4 = (float4*)&y_lds[sb][0];
        #pragma unroll
        for (int i = st; i < SEQT / 4; i += 128) yl4[i] = y4[i];
    }

    // Loop-invariant weights (SHARED by both chains -- same layer).
    // Gate order: i, f, g, o. i/f/o carry -log2e; g carries 2*log2e.
    const int wbase = l * 4 * HID;
    const float wi0 = -LOG2E * W_ih[wbase + 0 * HID + k];
    const float wi1 = -LOG2E * W_ih[wbase + 1 * HID + k];
    const float wi2 =  K2    * W_ih[wbase + 2 * HID + k];
    const float wi3 = -LOG2E * W_ih[wbase + 3 * HID + k];
    const float wh0 = -LOG2E * W_hh[wbase + 0 * HID + k];
    const float wh1 = -LOG2E * W_hh[wbase + 1 * HID + k];
    const float wh2 =  K2    * W_hh[wbase + 2 * HID + k];
    const float wh3 = -LOG2E * W_hh[wbase + 3 * HID + k];
    const float bb0 = -LOG2E * (b_ih[wbase + 0 * HID + k] + b_hh[wbase + 0 * HID + k]);
    const float bb1 = -LOG2E * (b_ih[wbase + 1 * HID + k] + b_hh[wbase + 1 * HID + k]);
    const float bb2 =  K2    * (b_ih[wbase + 2 * HID + k] + b_hh[wbase + 2 * HID + k]);
    const float bb3 = -LOG2E * (b_ih[wbase + 3 * HID + k] + b_hh[wbase + 3 * HID + k]);
    const float wr  = W_hr[l * HID + k];

    float hA = 0.0f, CA = 0.0f;   // chain A state
    float hB = 0.0f, CB = 0.0f;   // chain B state

    for (int p = 0; p < PHASES; ++p) {
        __syncthreads();   // publishes previous phase's h_buf writes (LDS only)
        const int t0 = (p - l) * CHUNK;
        if (t0 >= 0 && t0 < SEQT) {
            // Fetch both chains' 16 scalar inputs (wave-uniform broadcast reads).
            float4 xvA[CHUNK / 4], xvB[CHUNK / 4];
            if (l == 0) {
                const float4* ysA = (const float4*)&y_lds[0][t0];
                const float4* ysB = (const float4*)&y_lds[1][t0];
                #pragma unroll
                for (int q = 0; q < CHUNK / 4; ++q) { xvA[q] = ysA[q]; xvB[q] = ysB[q]; }
            } else {
                const float4* hbA = (const float4*)&h_buf[(p - 1) & 1][0][l - 1][0];
                const float4* hbB = (const float4*)&h_buf[(p - 1) & 1][1][l - 1][0];
                #pragma unroll
                for (int q = 0; q < CHUNK / 4; ++q) { xvA[q] = hbA[q]; xvB[q] = hbB[q]; }
            }
            float xsA[CHUNK], xsB[CHUNK];
            #pragma unroll
            for (int q = 0; q < CHUNK / 4; ++q) {
                xsA[4 * q + 0] = xvA[q].x; xsA[4 * q + 1] = xvA[q].y;
                xsA[4 * q + 2] = xvA[q].z; xsA[4 * q + 3] = xvA[q].w;
                xsB[4 * q + 0] = xvB[q].x; xsB[4 * q + 1] = xvB[q].y;
                xsB[4 * q + 2] = xvB[q].z; xsB[4 * q + 3] = xvB[q].w;
            }

            // Input-side gate contributions for both chains (off the chain).
            float pA0[CHUNK], pA1[CHUNK], pA2[CHUNK], pA3[CHUNK];
            float pB0[CHUNK], pB1[CHUNK], pB2[CHUNK], pB3[CHUNK];
            #pragma unroll
            for (int j = 0; j < CHUNK; ++j) {
                pA0[j] = fmaf(xsA[j], wi0, bb0);
                pA1[j] = fmaf(xsA[j], wi1, bb1);
                pA2[j] = fmaf(xsA[j], wi2, bb2);
                pA3[j] = fmaf(xsA[j], wi3, bb3);
                pB0[j] = fmaf(xsB[j], wi0, bb0);
                pB1[j] = fmaf(xsB[j], wi1, bb1);
                pB2[j] = fmaf(xsB[j], wi2, bb2);
                pB3[j] = fmaf(xsB[j], wi3, bb3);
            }

            float hcolA = 0.0f, hcolB = 0.0f;

            #pragma unroll
            for (int j = 0; j < CHUNK; ++j) {
                // ---- chain A step j ----
                const float giA = fmaf(hA, wh0, pA0[j]);
                const float gfA = fmaf(hA, wh1, pA1[j]);
                const float ggA = fmaf(hA, wh2, pA2[j]);
                const float goA = fmaf(hA, wh3, pA3[j]);
                const float EiA = fast_exp2(giA);
                const float EfA = fast_exp2(gfA);
                const float EgA = fast_exp2(ggA);
                const float EoA = fast_exp2(goA);
                const float denigA = (1.0f + EiA) * (1.0f + EgA);
                const float tgfA   = fmaf(K2, EgA, -K2) * (1.0f + EfA);
                const float numA   = fmaf(CA, denigA, tgfA);
                CA = numA * fast_rcp(denigA * (1.0f + EfA));
                const float EcA  = fast_exp2(CA);
                const float vA   = fmaf(wr, EcA, -wr) *
                                   fast_rcp((1.0f + EoA) * (1.0f + EcA));

                // ---- chain B step j (independent; fills A's stalls) ----
                const float giB = fmaf(hB, wh0, pB0[j]);
                const float gfB = fmaf(hB, wh1, pB1[j]);
                const float ggB = fmaf(hB, wh2, pB2[j]);
                const float goB = fmaf(hB, wh3, pB3[j]);
                const float EiB = fast_exp2(giB);
                const float EfB = fast_exp2(gfB);
                const float EgB = fast_exp2(ggB);
                const float EoB = fast_exp2(goB);
                const float denigB = (1.0f + EiB) * (1.0f + EgB);
                const float tgfB   = fmaf(K2, EgB, -K2) * (1.0f + EfB);
                const float numB   = fmaf(CB, denigB, tgfB);
                CB = numB * fast_rcp(denigB * (1.0f + EfB));
                const float EcB  = fast_exp2(CB);
                const float vB   = fmaf(wr, EcB, -wr) *
                                   fast_rcp((1.0f + EoB) * (1.0f + EcB));

                // ---- reduces (A's DPP chain overlaps B's gate math) ----
                const float vsA = wave_sum_lane63(vA);
                const float vsB = wave_sum_lane63(vB);
                hA = __int_as_float(
                    __builtin_amdgcn_readlane(__float_as_int(vsA), 63));
                hB = __int_as_float(
                    __builtin_amdgcn_readlane(__float_as_int(vsB), 63));

                // Branch-free collectors (lane j holds step j's h).
                hcolA = (k == j) ? hA : hcolA;
                hcolB = (k == j) ? hB : hcolB;
            }

            // One masked LDS store per phase per chain.
            if (k < CHUNK) {
                if (l < LAYERS - 1) {
                    h_buf[p & 1][0][l][k] = hcolA;
                    h_buf[p & 1][1][l][k] = hcolB;
                } else {
                    out_lds[0][t0 + k] = hcolA;
                    out_lds[1][t0 + k] = hcolB;
                }
            }
        }
    }

    // Flush buffered outputs to global once (coalesced per half-block).
    __syncthreads();
    const int nout = SEQT - msl;
    const int fb   = tid >> 7;            // batch within block (0..1)
    const int ft   = tid & 127;
    float* outb = out + (size_t)(blockIdx.x * BPW + fb) * nout;
    for (int i = ft; i < nout; i += 128) outb[i] = out_lds[fb][i + msl];
}

extern "C" void kernel_launch(void* const* d_in, const int* in_sizes, int n_in,
                              void* d_out, int out_size, void* d_ws, size_t ws_size,
                              hipStream_t stream) {
    const float* y    = (const float*)d_in[0];
    const float* W_ih = (const float*)d_in[1];
    const float* W_hh = (const float*)d_in[2];
    const float* b_ih = (const float*)d_in[3];
    const float* b_hh = (const float*)d_in[4];
    const float* W_hr = (const float*)d_in[5];
    const int*   msl  = (const int*)d_in[6];
    float* out = (float*)d_out;

    lstm_pipeline_kernel<<<GRID, 256, 0, stream>>>(
        y, W_ih, W_hh, b_ih, b_hh, W_hr, msl, out);
}

// Round 12
// 313.410 us; speedup vs baseline: 1.4535x; 1.2895x over previous
//
#include <hip/hip_runtime.h>

// Problem constants (fixed by the reference setup).
#define BATCH  256
#define SEQT   2048
#define LAYERS 4
#define CHUNK  32                        // timesteps per barrier phase
#define HALF   16                        // precompute granularity (VGPR cap)
#define PHASES (SEQT / CHUNK + LAYERS - 1)
// P (input / projected hidden size) == 1

#define LOG2E  1.4426950408889634f
#define K2     (2.0f * LOG2E)            // c is carried as C = K2 * c
#define HID    64

__device__ __forceinline__ float fast_rcp(float x) {
    return __builtin_amdgcn_rcpf(x);
}
__device__ __forceinline__ float fast_exp2(float x) {
    return __builtin_amdgcn_exp2f(x);    // raw v_exp_f32 (2^x)
}

// One DPP-shifted add: v += dpp_move(v). bound_ctrl=true -> invalid lanes read 0.
#define DPP_ADD(v, ctrl)                                                     \
    (v) += __int_as_float(__builtin_amdgcn_update_dpp(                       \
        0, __float_as_int(v), (ctrl), 0xF, 0xF, true))

// Full wave64 sum via DPP row reduce + row broadcasts; total lands in lane 63.
__device__ __forceinline__ float wave_sum_lane63(float v) {
    DPP_ADD(v, 0x111);   // row_shr:1
    DPP_ADD(v, 0x112);   // row_shr:2
    DPP_ADD(v, 0x114);   // row_shr:4
    DPP_ADD(v, 0x118);   // row_shr:8 -> lanes 15/31/47/63 = row sums
    DPP_ADD(v, 0x142);   // row_bcast:15
    DPP_ADD(v, 0x143);   // row_bcast:31 -> lane 63 = full sum
    return v;
}

// One block per batch element, 4 waves = 4 layers, 1 wave/SIMD (measured
// optimum: R6/R10/R11 showed every multi-chain packing is issue-additive --
// trans ops block issue ~16cy each and dominate -- so per-batch wall only
// drops by cheapening a SINGLE chain-step). Software pipeline across time in
// CHUNK=32-step phases (barriers halved vs CHUNK=16); inter-layer h via
// double-buffered LDS; outputs LDS-buffered, flushed once; phase body is one
// basic block with a cndmask collector; precompute done in two 16-step halves
// to cap VGPR pressure. 7 transcendentals/step (algebraic floor).
__global__ __launch_bounds__(256, 1) void lstm_pipeline_kernel(
    const float* __restrict__ y,      // [B, T, 1]
    const float* __restrict__ W_ih,   // [L, 4H, 1]
    const float* __restrict__ W_hh,   // [L, 4H, 1]
    const float* __restrict__ b_ih,   // [L, 4H]
    const float* __restrict__ b_hh,   // [L, 4H]
    const float* __restrict__ W_hr,   // [L, 1, H]
    const int*  __restrict__ msl_p,   // min_seq_len scalar
    float* __restrict__ out)          // [B, T - msl, 1]
{
    const int b   = blockIdx.x;
    const int tid = threadIdx.x;
    const int l   = tid >> 6;   // layer / wave id
    const int k   = tid & 63;   // hidden unit / lane
    const int msl = *msl_p;

    __shared__ float y_lds[SEQT];                              // 8 KB
    __shared__ float out_lds[SEQT];                            // 8 KB
    __shared__ __align__(16) float h_buf[2][LAYERS][CHUNK];    // inter-layer h

    // Stage y[b, :] into LDS with float4 loads.
    {
        const float4* y4  = (const float4*)(y + (size_t)b * SEQT);
        float4*       yl4 = (float4*)y_lds;
        #pragma unroll
        for (int i = tid; i < SEQT / 4; i += 256) yl4[i] = y4[i];
    }

    // Loop-invariant weights. Gate order: i, f, g, o.
    // i, f, o carry -log2e (exp2 -> e^-gate); g carries 2*log2e (exp2 -> e^{2g}).
    const int wbase = l * 4 * HID;
    const float wi0 = -LOG2E * W_ih[wbase + 0 * HID + k];
    const float wi1 = -LOG2E * W_ih[wbase + 1 * HID + k];
    const float wi2 =  K2    * W_ih[wbase + 2 * HID + k];
    const float wi3 = -LOG2E * W_ih[wbase + 3 * HID + k];
    const float wh0 = -LOG2E * W_hh[wbase + 0 * HID + k];
    const float wh1 = -LOG2E * W_hh[wbase + 1 * HID + k];
    const float wh2 =  K2    * W_hh[wbase + 2 * HID + k];
    const float wh3 = -LOG2E * W_hh[wbase + 3 * HID + k];
    const float bb0 = -LOG2E * (b_ih[wbase + 0 * HID + k] + b_hh[wbase + 0 * HID + k]);
    const float bb1 = -LOG2E * (b_ih[wbase + 1 * HID + k] + b_hh[wbase + 1 * HID + k]);
    const float bb2 =  K2    * (b_ih[wbase + 2 * HID + k] + b_hh[wbase + 2 * HID + k]);
    const float bb3 = -LOG2E * (b_ih[wbase + 3 * HID + k] + b_hh[wbase + 3 * HID + k]);
    const float wr  = W_hr[l * HID + k];

    float h = 0.0f;   // projected hidden (wave-uniform)
    float C = 0.0f;   // cell state, scaled: C = 2*log2e*c

    for (int p = 0; p < PHASES; ++p) {
        __syncthreads();   // publishes previous phase's h_buf writes (LDS only)
        const int t0 = (p - l) * CHUNK;
        if (t0 >= 0 && t0 < SEQT) {
            // Fetch this chunk's 32 scalar inputs (wave-uniform broadcast reads).
            float4 xv[CHUNK / 4];
            if (l == 0) {
                const float4* ys = (const float4*)&y_lds[t0];
                #pragma unroll
                for (int q = 0; q < CHUNK / 4; ++q) xv[q] = ys[q];
            } else {
                const float4* hb = (const float4*)&h_buf[(p - 1) & 1][l - 1][0];
                #pragma unroll
                for (int q = 0; q < CHUNK / 4; ++q) xv[q] = hb[q];
            }
            float xs[CHUNK];
            #pragma unroll
            for (int q = 0; q < CHUNK / 4; ++q) {
                xs[4 * q + 0] = xv[q].x; xs[4 * q + 1] = xv[q].y;
                xs[4 * q + 2] = xv[q].z; xs[4 * q + 3] = xv[q].w;
            }

            // Collector: lane j ends up holding step j's h (branch-free select).
            float hcol = 0.0f;

            // Two 16-step halves inside one barrier phase (precompute arrays
            // sized HALF to cap VGPR pressure).
            #pragma unroll
            for (int half = 0; half < CHUNK / HALF; ++half) {
                const int jb = half * HALF;

                // Input-side gate contributions: independent of h, off chain.
                float p0[HALF], p1[HALF], p2[HALF], p3[HALF];
                #pragma unroll
                for (int j = 0; j < HALF; ++j) {
                    const float x = xs[jb + j];
                    p0[j] = fmaf(x, wi0, bb0);
                    p1[j] = fmaf(x, wi1, bb1);
                    p2[j] = fmaf(x, wi2, bb2);
                    p3[j] = fmaf(x, wi3, bb3);
                }

                #pragma unroll
                for (int j = 0; j < HALF; ++j) {
                    // Gate pre-activations (scales pre-folded into weights).
                    const float gi = fmaf(h, wh0, p0[j]);
                    const float gf = fmaf(h, wh1, p1[j]);
                    const float gg = fmaf(h, wh2, p2[j]);
                    const float go = fmaf(h, wh3, p3[j]);

                    const float Ei = fast_exp2(gi);     // e^-i
                    const float Ef = fast_exp2(gf);     // e^-f
                    const float Eg = fast_exp2(gg);     // e^{2g}
                    const float Eo = fast_exp2(go);     // e^-o

                    // Merged c-update: one rcp for sf*C + si*tanh(g)*K2.
                    const float ai     = 1.0f + Ei;
                    const float ag     = 1.0f + Eg;
                    const float af     = 1.0f + Ef;
                    const float den_ig = ai * ag;
                    const float tg     = fmaf(K2, Eg, -K2);   // K2(Eg-1)
                    const float tgf    = tg * af;             // K2(Eg-1)(1+Ef)
                    const float num    = fmaf(C, den_ig, tgf);
                    const float den    = den_ig * af;
                    C = num * fast_rcp(den);

                    // Output: v = wr(Ec-1)/((1+Eo)(1+Ec)), one rcp.
                    const float Ec   = fast_exp2(C);          // e^{2c}
                    const float ao   = 1.0f + Eo;
                    const float ac   = 1.0f + Ec;
                    const float den2 = ao * ac;
                    const float num2 = fmaf(wr, Ec, -wr);     // wr(Ec-1)
                    const float v    = num2 * fast_rcp(den2);

                    const float vs = wave_sum_lane63(v);      // lane 63 = sum

                    // Wave-uniform h for the next step (readlane -> SGPR).
                    h = __int_as_float(
                        __builtin_amdgcn_readlane(__float_as_int(vs), 63));

                    // Deposit into lane (jb+j) of the collector -- no branch.
                    hcol = (k == jb + j) ? h : hcol;
                }
            }

            // One masked LDS store per phase (lanes 0..31 hold steps 0..31).
            if (k < CHUNK) {
                if (l < LAYERS - 1) h_buf[p & 1][l][k] = hcol;
                else                out_lds[t0 + k]    = hcol;
            }
        }
    }

    // Flush buffered outputs to global once (coalesced).
    __syncthreads();
    const int nout = SEQT - msl;
    float* outb = out + (size_t)b * nout;
    for (int i = tid; i < nout; i += 256) outb[i] = out_lds[i + msl];
}

extern "C" void kernel_launch(void* const* d_in, const int* in_sizes, int n_in,
                              void* d_out, int out_size, void* d_ws, size_t ws_size,
                              hipStream_t stream) {
    const float* y    = (const float*)d_in[0];
    const float* W_ih = (const float*)d_in[1];
    const float* W_hh = (const float*)d_in[2];
    const float* b_ih = (const float*)d_in[3];
    const float* b_hh = (const float*)d_in[4];
    const float* W_hr = (const float*)d_in[5];
    const int*   msl  = (const int*)d_in[6];
    float* out = (float*)d_out;

    lstm_pipeline_kernel<<<BATCH, 256, 0, stream>>>(
        y, W_ih, W_hh, b_ih, b_hh, W_hr, msl, out);
}

// Round 13
// 297.878 us; speedup vs baseline: 1.5293x; 1.0521x over previous
//
#include <hip/hip_runtime.h>

// Problem constants (fixed by the reference setup).
#define BATCH  256
#define SEQT   2048
#define LAYERS 4
#define CHUNK  32                        // timesteps per handoff chunk
#define HALF   16                        // precompute granularity (VGPR cap)
#define NCHUNK (SEQT / CHUNK)            // 64 chunks per layer
#define HID    64
// P (input / projected hidden size) == 1

#define LOG2E  1.4426950408889634f
#define K2     (2.0f * LOG2E)            // c is carried as C = K2 * c

__device__ __forceinline__ float fast_rcp(float x) {
    return __builtin_amdgcn_rcpf(x);
}
__device__ __forceinline__ float fast_exp2(float x) {
    return __builtin_amdgcn_exp2f(x);    // raw v_exp_f32 (2^x)
}

// One DPP-shifted add: v += dpp_move(v). bound_ctrl=true -> invalid lanes read 0.
#define DPP_ADD(v, ctrl)                                                     \
    (v) += __int_as_float(__builtin_amdgcn_update_dpp(                       \
        0, __float_as_int(v), (ctrl), 0xF, 0xF, true))

// Full wave64 sum via DPP row reduce + row broadcasts; total lands in lane 63.
__device__ __forceinline__ float wave_sum_lane63(float v) {
    DPP_ADD(v, 0x111);   // row_shr:1
    DPP_ADD(v, 0x112);   // row_shr:2
    DPP_ADD(v, 0x114);   // row_shr:4
    DPP_ADD(v, 0x118);   // row_shr:8 -> lanes 15/31/47/63 = row sums
    DPP_ADD(v, 0x142);   // row_bcast:15
    DPP_ADD(v, 0x143);   // row_bcast:31 -> lane 63 = full sum
    return v;
}

// One block per batch element, 4 waves = 4 layers, 1 wave/SIMD (measured
// optimum: R6/R10/R11 showed every multi-chain packing is issue-additive).
// ASYNC layer pipeline: no per-phase __syncthreads. Each inter-layer stream
// (2048 floats) lives ENTIRELY in LDS, so producers never wait (no
// back-pressure) and consumers wait only during initial fill; handoff is a
// volatile LDS chunk-counter per layer with __threadfence_block for
// release/acquire ordering. This removes the measured ~500 cy/phase lockstep
// cost of s_barrier (R9->R12 delta per removed barrier).
// Per step: 7 transcendentals (5 exp2 + 2 rcp -- algebraic floor), merged-rcp
// c-update, DPP reduce, cndmask collector, one masked LDS store per chunk.
__global__ __launch_bounds__(256, 1) void lstm_pipeline_kernel(
    const float* __restrict__ y,      // [B, T, 1]
    const float* __restrict__ W_ih,   // [L, 4H, 1]
    const float* __restrict__ W_hh,   // [L, 4H, 1]
    const float* __restrict__ b_ih,   // [L, 4H]
    const float* __restrict__ b_hh,   // [L, 4H]
    const float* __restrict__ W_hr,   // [L, 1, H]
    const int*  __restrict__ msl_p,   // min_seq_len scalar
    float* __restrict__ out)          // [B, T - msl, 1]
{
    const int b   = blockIdx.x;
    const int tid = threadIdx.x;
    const int l   = tid >> 6;   // layer / wave id
    const int k   = tid & 63;   // hidden unit / lane
    const int msl = *msl_p;

    __shared__ float y_lds[SEQT];                  //  8 KB: layer-0 input
    __shared__ float inter[LAYERS - 1][SEQT];      // 24 KB: inter-layer h streams
    __shared__ float out_lds[SEQT];                //  8 KB: final outputs
    __shared__ int   flags[LAYERS];                // chunks published per layer

    // Stage y[b, :] into LDS with float4 loads; init handoff flags.
    {
        const float4* y4  = (const float4*)(y + (size_t)b * SEQT);
        float4*       yl4 = (float4*)y_lds;
        #pragma unroll
        for (int i = tid; i < SEQT / 4; i += 256) yl4[i] = y4[i];
        if (tid < LAYERS) flags[tid] = 0;
    }

    // Loop-invariant weights. Gate order: i, f, g, o.
    // i, f, o carry -log2e (exp2 -> e^-gate); g carries 2*log2e (exp2 -> e^{2g}).
    const int wbase = l * 4 * HID;
    const float wi0 = -LOG2E * W_ih[wbase + 0 * HID + k];
    const float wi1 = -LOG2E * W_ih[wbase + 1 * HID + k];
    const float wi2 =  K2    * W_ih[wbase + 2 * HID + k];
    const float wi3 = -LOG2E * W_ih[wbase + 3 * HID + k];
    const float wh0 = -LOG2E * W_hh[wbase + 0 * HID + k];
    const float wh1 = -LOG2E * W_hh[wbase + 1 * HID + k];
    const float wh2 =  K2    * W_hh[wbase + 2 * HID + k];
    const float wh3 = -LOG2E * W_hh[wbase + 3 * HID + k];
    const float bb0 = -LOG2E * (b_ih[wbase + 0 * HID + k] + b_hh[wbase + 0 * HID + k]);
    const float bb1 = -LOG2E * (b_ih[wbase + 1 * HID + k] + b_hh[wbase + 1 * HID + k]);
    const float bb2 =  K2    * (b_ih[wbase + 2 * HID + k] + b_hh[wbase + 2 * HID + k]);
    const float bb3 = -LOG2E * (b_ih[wbase + 3 * HID + k] + b_hh[wbase + 3 * HID + k]);
    const float wr  = W_hr[l * HID + k];

    __syncthreads();   // y_lds + flags visible to all waves (the ONLY mid-kernel barrier)

    float h = 0.0f;   // projected hidden (wave-uniform)
    float C = 0.0f;   // cell state, scaled: C = 2*log2e*c

    volatile int* vflags = flags;

    for (int c = 0; c < NCHUNK; ++c) {
        const int t0 = c * CHUNK;

        // Acquire: wait until layer l-1 has published chunk c (steady state:
        // falls through immediately -- the full-sequence buffer means the
        // producer is always ahead after the initial fill).
        if (l > 0) {
            while (vflags[l - 1] <= c) __builtin_amdgcn_s_sleep(1);
            __threadfence_block();
        }

        // Fetch this chunk's 32 scalar inputs (wave-uniform broadcast reads).
        const float* src = (l == 0) ? &y_lds[t0] : &inter[l - 1][t0];
        float4 xv[CHUNK / 4];
        {
            const float4* s4 = (const float4*)src;
            #pragma unroll
            for (int q = 0; q < CHUNK / 4; ++q) xv[q] = s4[q];
        }
        float xs[CHUNK];
        #pragma unroll
        for (int q = 0; q < CHUNK / 4; ++q) {
            xs[4 * q + 0] = xv[q].x; xs[4 * q + 1] = xv[q].y;
            xs[4 * q + 2] = xv[q].z; xs[4 * q + 3] = xv[q].w;
        }

        // Collector: lane j ends up holding step j's h (branch-free select).
        float hcol = 0.0f;

        // Two 16-step halves per chunk (precompute arrays sized HALF to cap
        // VGPR pressure).
        #pragma unroll
        for (int half = 0; half < CHUNK / HALF; ++half) {
            const int jb = half * HALF;

            // Input-side gate contributions: independent of h, off chain.
            float p0[HALF], p1[HALF], p2[HALF], p3[HALF];
            #pragma unroll
            for (int j = 0; j < HALF; ++j) {
                const float x = xs[jb + j];
                p0[j] = fmaf(x, wi0, bb0);
                p1[j] = fmaf(x, wi1, bb1);
                p2[j] = fmaf(x, wi2, bb2);
                p3[j] = fmaf(x, wi3, bb3);
            }

            #pragma unroll
            for (int j = 0; j < HALF; ++j) {
                // Gate pre-activations (scales pre-folded into weights).
                const float gi = fmaf(h, wh0, p0[j]);
                const float gf = fmaf(h, wh1, p1[j]);
                const float gg = fmaf(h, wh2, p2[j]);
                const float go = fmaf(h, wh3, p3[j]);

                const float Ei = fast_exp2(gi);     // e^-i
                const float Ef = fast_exp2(gf);     // e^-f
                const float Eg = fast_exp2(gg);     // e^{2g}
                const float Eo = fast_exp2(go);     // e^-o

                // Merged c-update: one rcp for sf*C + si*tanh(g)*K2.
                const float ai     = 1.0f + Ei;
                const float ag     = 1.0f + Eg;
                const float af     = 1.0f + Ef;
                const float den_ig = ai * ag;
                const float tg     = fmaf(K2, Eg, -K2);   // K2(Eg-1)
                const float tgf    = tg * af;             // K2(Eg-1)(1+Ef)
                const float num    = fmaf(C, den_ig, tgf);
                const float den    = den_ig * af;
                C = num * fast_rcp(den);

                // Output: v = wr(Ec-1)/((1+Eo)(1+Ec)), one rcp.
                const float Ec   = fast_exp2(C);          // e^{2c}
                const float ao   = 1.0f + Eo;
                const float ac   = 1.0f + Ec;
                const float den2 = ao * ac;
                const float num2 = fmaf(wr, Ec, -wr);     // wr(Ec-1)
                const float v    = num2 * fast_rcp(den2);

                const float vs = wave_sum_lane63(v);      // lane 63 = sum

                // Wave-uniform h for the next step (readlane -> SGPR).
                h = __int_as_float(
                    __builtin_amdgcn_readlane(__float_as_int(vs), 63));

                // Deposit into lane (jb+j) of the collector -- no branch.
                hcol = (k == jb + j) ? h : hcol;
            }
        }

        // Publish chunk c (lanes 0..31 hold steps 0..31).
        if (l < LAYERS - 1) {
            if (k < CHUNK) inter[l][t0 + k] = hcol;
            __threadfence_block();                 // release: data before flag
            if (k == 0) vflags[l] = c + 1;
        } else {
            if (k < CHUNK) out_lds[t0 + k] = hcol; // no consumer to signal
        }
    }

    // Flush buffered outputs to global once (coalesced).
    __syncthreads();
    const int nout = SEQT - msl;
    float* outb = out + (size_t)b * nout;
    for (int i = tid; i < nout; i += 256) outb[i] = out_lds[i + msl];
}

extern "C" void kernel_launch(void* const* d_in, const int* in_sizes, int n_in,
                              void* d_out, int out_size, void* d_ws, size_t ws_size,
                              hipStream_t stream) {
    const float* y    = (const float*)d_in[0];
    const float* W_ih = (const float*)d_in[1];
    const float* W_hh = (const float*)d_in[2];
    const float* b_ih = (const float*)d_in[3];
    const float* b_hh = (const float*)d_in[4];
    const float* W_hr = (const float*)d_in[5];
    const int*   msl  = (const int*)d_in[6];
    float* out = (float*)d_out;

    lstm_pipeline_kernel<<<BATCH, 256, 0, stream>>>(
        y, W_ih, W_hh, b_ih, b_hh, W_hr, msl, out);
}